// Round 17
// baseline (140.085 us; speedup 1.0000x reference)
//
#include <hip/hip_runtime.h>
#include <math.h>

#define ALPHA 0.2f
#define NP 50000
#define NA 25000
#define NBINS 150000          // P: 2*NP interleaved bins, then A: 2*NA
#define ABASE 100000          // bin base for A nodes
#define NBUCK 586             // ceil(NBINS/256)
#define CH 4096               // edges per scatter block (= 16*256, static unroll)
#define CAP 8192              // fixed bucket region capacity in ebuf (max observed ~3.9k)
#define GP ((NP + 63) / 64)   // 782 xform row-blocks for P
#define GA ((NA + 63) / 64)   // 391 xform row-blocks for A
#define XWI_P (3 * GP)        // 2346 P wave-items
#define XWI (3 * GP + 3 * GA) // 3519 total wave-items
#define XWB ((XWI + 3) / 4)   // 880 xform blocks (4 wave-items each)
#define SB_P 384              // state-accum blocks for P
#define SB_A 192              // state-accum blocks for A

typedef unsigned short u16;
typedef __attribute__((ext_vector_type(8))) short bf16x8;
typedef __attribute__((ext_vector_type(8))) unsigned short u16x8;
typedef __attribute__((ext_vector_type(4))) float f32x4;

__device__ __forceinline__ float bf2f(u16 u) { return __uint_as_float(((unsigned)u) << 16); }
__device__ __forceinline__ u16 f2bf(float f) {
    unsigned x = __float_as_uint(f);
    return (u16)((x + 0x7fffu + ((x >> 16) & 1u)) >> 16);   // RNE
}

// =============== args ===============
struct K1Args {      // scatter | xform (wave-items) | state-accumulate
    const int *s0, *d0, *s1, *d1, *s2, *d2, *s3, *d3;
    int E0, E1, E2, E3, Etot, nblk;
    int *cursor0, *ebuf;
    const float *feat_P, *feat_A, *feat_S;
    // xform weights/dots
    const float *W_P, *b_P, *W_A, *b_A, *W_p2p, *b_p2p, *W_p2a, *b_p2a,
                *W_a2p, *b_a2p, *W_a2a, *b_a2a;
    const float *a_p2p, *a_p2a, *a_a2p, *a_a2a;
    float *WhP, *WhA;
    u16 *z_p2p, *z_p2a, *z_a2p, *z_a2a;
    float *ss_p2p, *sd_p2p, *ss_p2a, *sd_p2a, *ss_a2p, *sd_a2p, *ss_a2a, *sd_a2a;
    // state (linearity trick)
    const float *W_p2s, *b_p2s, *a_p2s, *W_a2s, *b_a2s, *a_a2s, *W_in, *b_in;
    float *numP, *numA, *den2;
};

struct K2Args {      // fine_sort | finalize
    const int *ebuf; const int *cursor0;
    u16 *ssrc; int *offs;
    const float *feat_S;
    const float *W_p2s, *b_p2s, *W_a2s, *b_a2s, *W_in, *b_in;
    const float *numP, *numA, *den2;
    float *outS;
};

// =============== edge decode ===============
__device__ __forceinline__ void edge_decode(int k,
    const int* __restrict__ s0, const int* __restrict__ d0, int E0,
    const int* __restrict__ s1, const int* __restrict__ d1, int E1,
    const int* __restrict__ s2, const int* __restrict__ d2, int E2,
    const int* __restrict__ s3, const int* __restrict__ d3,
    int& src, int& bin) {
    if (k < E0) { src = s0[k]; bin = 2 * d0[k]; return; }
    k -= E0; if (k < E1) { src = s1[k]; bin = 2 * d1[k] + 1; return; }
    k -= E1; if (k < E2) { src = s2[k]; bin = ABASE + 2 * d2[k]; return; }
    k -= E2; src = s3[k]; bin = ABASE + 2 * d3[k] + 1;
}

// =============== per-wave xform item: 64 rows x ONE matrix ===============
__device__ __forceinline__ void xform_item(int rb,
    const float* __restrict__ X, int N,
    const float* __restrict__ Wm, const float* __restrict__ bm,
    const float* __restrict__ dv, float* __restrict__ sm,
    const float* __restrict__ dB, float* __restrict__ sdB,   // only m==0 (else null)
    float* __restrict__ whout, u16* __restrict__ zm,          // exactly one non-null
    int lane)
{
    int g = lane >> 4, li = lane & 15;
    bf16x8 Bf[4][2];
#pragma unroll
    for (int cb = 0; cb < 4; ++cb)
#pragma unroll
        for (int kc = 0; kc < 2; ++kc) {
            bf16x8 t;
#pragma unroll
            for (int j = 0; j < 8; ++j)
                t[j] = (short)f2bf(Wm[(kc * 32 + g * 8 + j) * 64 + cb * 16 + li]);
            Bf[cb][kc] = t;
        }
    float bl[4], dvl[4], dbl[4];
#pragma unroll
    for (int cb = 0; cb < 4; ++cb) {
        bl[cb]  = bm[cb * 16 + li];
        dvl[cb] = dv[cb * 16 + li];
        dbl[cb] = sdB ? dB[cb * 16 + li] : 0.f;
    }
    int base0 = rb * 64;
#pragma unroll
    for (int rt = 0; rt < 4; ++rt) {
        int rbase = base0 + rt * 16;
        if (rbase >= N) break;
        int rowC = min(rbase + li, N - 1);
        bf16x8 Af[2];
#pragma unroll
        for (int kc = 0; kc < 2; ++kc) {
            const float* xp = X + (long long)rowC * 64 + kc * 32 + g * 8;
            float4 x0 = *(const float4*)xp;
            float4 x1 = *(const float4*)(xp + 4);
            bf16x8 t;
            t[0] = (short)f2bf(x0.x); t[1] = (short)f2bf(x0.y);
            t[2] = (short)f2bf(x0.z); t[3] = (short)f2bf(x0.w);
            t[4] = (short)f2bf(x1.x); t[5] = (short)f2bf(x1.y);
            t[6] = (short)f2bf(x1.z); t[7] = (short)f2bf(x1.w);
            Af[kc] = t;
        }
        f32x4 acc[4] = {{0,0,0,0},{0,0,0,0},{0,0,0,0},{0,0,0,0}};
#pragma unroll
        for (int kc = 0; kc < 2; ++kc)
#pragma unroll
            for (int cb = 0; cb < 4; ++cb)
                acc[cb] = __builtin_amdgcn_mfma_f32_16x16x32_bf16(Af[kc], Bf[cb][kc], acc[cb], 0, 0, 0);
        float pd[4] = {0,0,0,0}, pb[4] = {0,0,0,0};
#pragma unroll
        for (int cb = 0; cb < 4; ++cb)
#pragma unroll
            for (int r = 0; r < 4; ++r) {
                float val = acc[cb][r] + bl[cb];
                acc[cb][r] = val;
                pd[r] = fmaf(val, dvl[cb], pd[r]);
                pb[r] = fmaf(val, dbl[cb], pb[r]);
            }
#pragma unroll
        for (int o = 1; o < 16; o <<= 1)
#pragma unroll
            for (int r = 0; r < 4; ++r) {
                pd[r] += __shfl_xor(pd[r], o, 64);
                pb[r] += __shfl_xor(pb[r], o, 64);
            }
        int rg = rbase + g * 4;
        if (li == 0) {
#pragma unroll
            for (int r = 0; r < 4; ++r) {
                int row = rg + r;
                if (row < N) {
                    sm[row] = pd[r];
                    if (sdB) sdB[row] = pb[r];
                }
            }
        }
        if (whout) {
#pragma unroll
            for (int r = 0; r < 4; ++r) {
                int row = rg + r;
                if (row < N)
#pragma unroll
                    for (int cb = 0; cb < 4; ++cb)
                        whout[(long long)row * 64 + cb * 16 + li] = acc[cb][r];
            }
        } else {
#pragma unroll
            for (int r = 0; r < 4; ++r) {
                int row = rg + r;
                if (row < N)
#pragma unroll
                    for (int cb = 0; cb < 4; ++cb)
                        zm[(long long)row * 64 + cb * 16 + li] = f2bf(acc[cb][r]);
            }
        }
    }
}

// =============== k1: scatter | xform wave-items | state-accumulate ===============
__global__ __launch_bounds__(256) void k1_kernel(K1Args A) {
    __shared__ int h[NBUCK];
    __shared__ int base[NBUCK];
    int bid = blockIdx.x;
    int tid = threadIdx.x, lane = tid & 63, wv = tid >> 6;
    if (bid < A.nblk) {
        // ---- scatter role: window reservation into fixed bucket regions ----
        for (int i = tid; i < NBUCK; i += 256) h[i] = 0;
        __syncthreads();
        int b0 = bid * CH;
        int b1 = min(b0 + CH, A.Etot);
        int cbin[16], csrc[16];
#pragma unroll
        for (int it = 0; it < 16; ++it) {
            int i = b0 + it * 256 + tid;
            int bin = -1, src = 0;
            if (i < b1)
                edge_decode(i, A.s0, A.d0, A.E0, A.s1, A.d1, A.E1,
                            A.s2, A.d2, A.E2, A.s3, A.d3, src, bin);
            cbin[it] = bin; csrc[it] = src;
            if (bin >= 0) atomicAdd(&h[bin >> 8], 1);
        }
        __syncthreads();
        for (int i = tid; i < NBUCK; i += 256) {
            int c = h[i];
            base[i] = c ? (i * CAP + atomicAdd(&A.cursor0[i], c)) : 0;
            h[i] = 0;                           // reuse as local cursor
        }
        __syncthreads();
#pragma unroll
        for (int it = 0; it < 16; ++it) {
            int bin = cbin[it];
            if (bin >= 0) {
                int bk = bin >> 8;
                int pos = base[bk] + atomicAdd(&h[bk], 1);
                if (pos < (bk + 1) * CAP)       // capacity guard (never hit)
                    A.ebuf[pos] = csrc[it] | ((bin & 255) << 16);
            }
        }
        return;
    }
    bid -= A.nblk;
    if (bid < XWB) {
        // ---- xform role: one wave-item = (type, matrix, 64-row block) ----
        int item = bid * 4 + wv;
        if (item >= XWI) return;                // wave-uniform
        bool isP = item < XWI_P;
        int m, rb;
        if (isP) { m = item / GP; rb = item % GP; }
        else     { int it2 = item - XWI_P; m = it2 / GA; rb = it2 % GA; }
        const float* X = isP ? A.feat_P : A.feat_A;
        int N = isP ? NP : NA;
        const float *Wm, *bm, *dv, *dB = nullptr;
        float *sm, *sdB = nullptr, *whout = nullptr;
        u16 *zm = nullptr;
        if (isP) {
            if (m == 0)      { Wm = A.W_P;   bm = A.b_P;   dv = A.a_p2p + 64; sm = A.sd_p2p;
                               dB = A.a_a2p + 64; sdB = A.sd_a2p; whout = A.WhP; }
            else if (m == 1) { Wm = A.W_p2p; bm = A.b_p2p; dv = A.a_p2p; sm = A.ss_p2p; zm = A.z_p2p; }
            else             { Wm = A.W_p2a; bm = A.b_p2a; dv = A.a_p2a; sm = A.ss_p2a; zm = A.z_p2a; }
        } else {
            if (m == 0)      { Wm = A.W_A;   bm = A.b_A;   dv = A.a_p2a + 64; sm = A.sd_p2a;
                               dB = A.a_a2a + 64; sdB = A.sd_a2a; whout = A.WhA; }
            else if (m == 1) { Wm = A.W_a2p; bm = A.b_a2p; dv = A.a_a2p; sm = A.ss_a2p; zm = A.z_a2p; }
            else             { Wm = A.W_a2a; bm = A.b_a2a; dv = A.a_a2a; sm = A.ss_a2a; zm = A.z_a2a; }
        }
        xform_item(rb, X, N, Wm, bm, dv, sm, dB, sdB, whout, zm, lane);
        return;
    }
    bid -= XWB;
    // ---- state-accumulate role: num_raw += w*x, den += w over ALL nodes ----
    float* red = (float*)h;                     // reuse LDS
    bool isP = bid < SB_P;
    int bidl = isP ? bid : bid - SB_P;
    int nb = isP ? SB_P : SB_A;
    int N = isP ? NP : NA;
    const float* X   = isP ? A.feat_P : A.feat_A;
    const float* W   = isP ? A.W_p2s  : A.W_a2s;
    const float* b   = isP ? A.b_p2s  : A.b_a2s;
    const float* a   = isP ? A.a_p2s  : A.a_a2s;   // [128]: src-half then dst-half
    float* num       = isP ? A.numP   : A.numA;
    float* den       = isP ? &A.den2[0] : &A.den2[1];
    float v = 0.f;
    for (int c = 0; c < 64; ++c) v = fmaf(W[lane * 64 + c], a[c], v);
    float t0 = b[lane] * a[lane];
    float whc = A.b_in[lane];
    for (int k = 0; k < 64; ++k) whc = fmaf(A.feat_S[k], A.W_in[k * 64 + lane], whc);
    float t1 = whc * a[64 + lane];
#pragma unroll
    for (int o = 1; o < 64; o <<= 1) {
        t0 += __shfl_xor(t0, o, 64);
        t1 += __shfl_xor(t1, o, 64);
    }
    float cbias = t0 + t1;
    float accx = 0.f, accd = 0.f;
    int gw = bidl * 4 + wv, waves = nb * 4;
    for (int r = gw; r < N; r += waves) {
        float x = X[(long long)r * 64 + lane];  // coalesced
        float ss = x * v;
#pragma unroll
        for (int o = 1; o < 64; o <<= 1) ss += __shfl_xor(ss, o, 64);
        float e = ss + cbias;
        e = e > 0.f ? e : ALPHA * e;
        float w = __expf(e);
        accx = fmaf(w, x, accx);
        accd += w;
    }
    red[wv * 64 + lane] = accx;
    if (lane == 0) red[256 + wv] = accd;
    __syncthreads();
    if (tid < 64) {
        float t = red[tid] + red[64 + tid] + red[128 + tid] + red[192 + tid];
        atomicAdd(&num[tid], t);
    }
    if (tid == 64) atomicAdd(den, red[256] + red[257] + red[258] + red[259]);
}

// =============== in-block exclusive scan of 586 bucket counts (clamped to CAP) ===============
__device__ void scan_counts(const int* __restrict__ counts, int* sstart) {
    __shared__ int wtot_sb[4];
    int tid = threadIdx.x, lane = tid & 63, wv = tid >> 6;
    int carry = 0;
    for (int c = 0; c < 3; ++c) {
        int i = c * 256 + tid;
        int v = (i < NBUCK) ? min(counts[i], CAP) : 0;
        int x = v;
#pragma unroll
        for (int o = 1; o < 64; o <<= 1) {
            int y = __shfl_up(x, o, 64);
            if (lane >= o) x += y;
        }
        if (lane == 63) wtot_sb[wv] = x;
        __syncthreads();
        int woff = carry;
        for (int j = 0; j < wv; ++j) woff += wtot_sb[j];
        int ctot = wtot_sb[0] + wtot_sb[1] + wtot_sb[2] + wtot_sb[3];
        if (i < NBUCK) sstart[i] = x + woff - v;
        __syncthreads();
        carry += ctot;
    }
    if (tid == 0) sstart[NBUCK] = carry;
    __syncthreads();
}

// =============== k2: fine_sort (packed, u16 ssrc) | state finalize ===============
__global__ __launch_bounds__(256) void k2_kernel(K2Args A) {
    __shared__ int smem_i[NBUCK + 1 + 768 + 4];     // sstart | lcnt | loff | lcur | wtot
    __shared__ u16 lsrc[CAP];
    int bid = blockIdx.x;
    int tid = threadIdx.x, lane = tid & 63, wv = tid >> 6;
    if (bid < NBUCK) {
        int* sstart = smem_i;
        int* lcnt = smem_i + NBUCK + 1;
        int* loff = lcnt + 256;
        int* lcur = loff + 256;
        int* wtot = lcur + 256;
        int b = bid;
        scan_counts(A.cursor0, sstart);
        int pstart = sstart[b];
        int rstart = b * CAP;
        int cnt = min(A.cursor0[b], CAP);
        lcnt[tid] = 0;
        __syncthreads();
        for (int e = tid; e < cnt; e += 256)
            atomicAdd(&lcnt[((unsigned)A.ebuf[rstart + e]) >> 16], 1);
        __syncthreads();
        int v = lcnt[tid];
        int x = v;
#pragma unroll
        for (int o = 1; o < 64; o <<= 1) {
            int y = __shfl_up(x, o, 64);
            if (lane >= o) x += y;
        }
        if (lane == 63) wtot[wv] = x;
        __syncthreads();
        int woff = 0;
        for (int j = 0; j < wv; ++j) woff += wtot[j];
        int excl = x + woff - v;
        loff[tid] = excl;
        lcur[tid] = excl;
        __syncthreads();
        for (int e = tid; e < cnt; e += 256) {
            int val = A.ebuf[rstart + e];
            int pos = atomicAdd(&lcur[((unsigned)val) >> 16], 1);
            lsrc[pos] = (u16)(val & 0xFFFF);
        }
        __syncthreads();
        for (int i = tid; i < cnt; i += 256) A.ssrc[pstart + i] = lsrc[i];   // coalesced u16
        int gb = b * 256 + tid;
        if (gb < NBINS) A.offs[gb] = pstart + loff[tid];
        if (b == 0 && tid == 0) A.offs[NBINS] = sstart[NBUCK];
        return;
    }
    // ---- finalize: outS = relu(Wh_in + (numP@W_p2s + b_p2s*den)/den + ...) ----
    if (tid < 64) {
        int c = tid;
        float whc = A.b_in[c];
        for (int k = 0; k < 64; ++k) whc = fmaf(A.feat_S[k], A.W_in[k * 64 + c], whc);
        float mp = 0.f, ma = 0.f;
        for (int k = 0; k < 64; ++k) {
            mp = fmaf(A.numP[k], A.W_p2s[k * 64 + c], mp);
            ma = fmaf(A.numA[k], A.W_a2s[k * 64 + c], ma);
        }
        float r = whc + mp / A.den2[0] + A.b_p2s[c] + ma / A.den2[1] + A.b_a2s[c];
        A.outS[c] = fmaxf(r, 0.f);
    }
}

// =============== per-segment gather, 8 edges in flight (R8 structure, u16 ssrc) ===============
__device__ __forceinline__ void seg_gat_g8(const u16* __restrict__ ssrc, int s0, int s1,
                                           const float* __restrict__ ss, float sd,
                                           const u16* __restrict__ z, int lane,
                                           float* __restrict__ acc) {
    int cnt = s1 - s0;
    if (cnt <= 0) return;
    int egrp = lane >> 3, cg8 = (lane & 7) * 8;
    if (cnt <= 64) {                    // fast path (deg <= 64: essentially always)
        int s = 0; float w = 0.f;
        if (lane < cnt) {
            s = (int)ssrc[s0 + lane];   // coalesced u16
            float e = ss[s] + sd;
            e = e > 0.f ? e : ALPHA * e;
            w = __expf(e);
        }
        float den = w;
#pragma unroll
        for (int o = 32; o > 0; o >>= 1) den += __shfl_xor(den, o, 64);
        w *= 1.f / den;
        int nit = (cnt + 7) >> 3;
        for (int it = 0; it < nit; ++it) {
            int ei = it * 8 + egrp;
            float wt = __shfl(w, ei, 64);   // 0 for ei >= cnt
            int   st = __shfl(s, ei, 64);
            u16x8 q = *(const u16x8*)(z + (long long)st * 64 + cg8);
#pragma unroll
            for (int j = 0; j < 8; ++j)
                acc[j] = fmaf(wt, bf2f(q[j]), acc[j]);
        }
    } else {                            // general path (rare)
        float den = 0.f;
        for (int i = s0 + lane; i < s1; i += 64) {
            float e = ss[(int)ssrc[i]] + sd; e = e > 0.f ? e : ALPHA * e; den += __expf(e);
        }
#pragma unroll
        for (int o = 32; o > 0; o >>= 1) den += __shfl_xor(den, o, 64);
        float inv = 1.f / den;
        for (int c = s0; c < s1; c += 64) {
            int i = c + lane; int s = 0; float w = 0.f;
            if (i < s1) {
                s = (int)ssrc[i];
                float e = ss[s] + sd; e = e > 0.f ? e : ALPHA * e;
                w = __expf(e) * inv;
            }
            int cc = min(64, s1 - c);
            int nit = (cc + 7) >> 3;
            for (int it = 0; it < nit; ++it) {
                int ei = it * 8 + egrp;
                float wt = __shfl(w, ei, 64);
                int   st = __shfl(s, ei, 64);
                u16x8 q = *(const u16x8*)(z + (long long)st * 64 + cg8);
#pragma unroll
                for (int j = 0; j < 8; ++j)
                    acc[j] = fmaf(wt, bf2f(q[j]), acc[j]);
            }
        }
    }
}

// =============== gat_all: PURE kernel (R8-proven) ===============
__global__ __launch_bounds__(256) void gat_all(
    const u16* __restrict__ ssrc, const int* __restrict__ offs,
    const float* __restrict__ WhP, float* __restrict__ outP,
    const float* __restrict__ WhA, float* __restrict__ outA,
    const float* __restrict__ ss_p2p, const float* __restrict__ sd_p2p, const u16* __restrict__ z_p2p,
    const float* __restrict__ ss_a2p, const float* __restrict__ sd_a2p, const u16* __restrict__ z_a2p,
    const float* __restrict__ ss_p2a, const float* __restrict__ sd_p2a, const u16* __restrict__ z_p2a,
    const float* __restrict__ ss_a2a, const float* __restrict__ sd_a2a, const u16* __restrict__ z_a2a) {
    int lane = threadIdx.x & 63;
    int g = (blockIdx.x * blockDim.x + threadIdx.x) >> 6;   // wave id = node id
    if (g >= NP + NA) return;                               // wave-uniform
    bool isP = g < NP;
    int d = isP ? g : g - NP;
    int bin0 = isP ? 2 * d : ABASE + 2 * d;
    int e0 = offs[bin0], e1 = offs[bin0 + 1], e2 = offs[bin0 + 2];
    float acc[8] = {0.f, 0.f, 0.f, 0.f, 0.f, 0.f, 0.f, 0.f};
    if (isP) {
        seg_gat_g8(ssrc, e0, e1, ss_p2p, sd_p2p[d], z_p2p, lane, acc);
        seg_gat_g8(ssrc, e1, e2, ss_a2p, sd_a2p[d], z_a2p, lane, acc);
    } else {
        seg_gat_g8(ssrc, e0, e1, ss_p2a, sd_p2a[d], z_p2a, lane, acc);
        seg_gat_g8(ssrc, e1, e2, ss_a2a, sd_a2a[d], z_a2a, lane, acc);
    }
#pragma unroll
    for (int o = 8; o <= 32; o <<= 1)
#pragma unroll
        for (int j = 0; j < 8; ++j)
            acc[j] += __shfl_xor(acc[j], o, 64);
    if (lane < 8) {
        const float* Wh = isP ? WhP : WhA;
        float* outp = isP ? outP : outA;
        const float* sp = &Wh[(long long)d * 64 + lane * 8];
        float4 s0v = *(const float4*)sp;
        float4 s1v = *(const float4*)(sp + 4);
        float4 r0, r1;
        r0.x = fmaxf(s0v.x + acc[0], 0.f); r0.y = fmaxf(s0v.y + acc[1], 0.f);
        r0.z = fmaxf(s0v.z + acc[2], 0.f); r0.w = fmaxf(s0v.w + acc[3], 0.f);
        r1.x = fmaxf(s1v.x + acc[4], 0.f); r1.y = fmaxf(s1v.y + acc[5], 0.f);
        r1.z = fmaxf(s1v.z + acc[6], 0.f); r1.w = fmaxf(s1v.w + acc[7], 0.f);
        float* op = &outp[(long long)d * 64 + lane * 8];
        *(float4*)op = r0;
        *(float4*)(op + 4) = r1;
    }
}

extern "C" void kernel_launch(void* const* d_in, const int* in_sizes, int n_in,
                              void* d_out, int out_size, void* d_ws, size_t ws_size,
                              hipStream_t stream) {
    const float* feat_P = (const float*)d_in[0];
    const float* feat_A = (const float*)d_in[1];
    const float* feat_S = (const float*)d_in[2];
    const float* W_P   = (const float*)d_in[3];  const float* b_P   = (const float*)d_in[4];
    const float* W_A   = (const float*)d_in[5];  const float* b_A   = (const float*)d_in[6];
    const float* W_p2p = (const float*)d_in[7];  const float* b_p2p = (const float*)d_in[8];
    const float* W_p2a = (const float*)d_in[9];  const float* b_p2a = (const float*)d_in[10];
    const float* W_a2p = (const float*)d_in[11]; const float* b_a2p = (const float*)d_in[12];
    const float* W_a2a = (const float*)d_in[13]; const float* b_a2a = (const float*)d_in[14];
    const float* W_p2s = (const float*)d_in[15]; const float* b_p2s = (const float*)d_in[16];
    const float* W_a2s = (const float*)d_in[17]; const float* b_a2s = (const float*)d_in[18];
    const float* W_in  = (const float*)d_in[19]; const float* b_in  = (const float*)d_in[20];
    const float* a_p2p = (const float*)d_in[21];
    const float* a_p2a = (const float*)d_in[22];
    const float* a_a2p = (const float*)d_in[23];
    const float* a_a2a = (const float*)d_in[24];
    const float* a_p2s = (const float*)d_in[25];
    const float* a_a2s = (const float*)d_in[26];
    const int* src_p2p = (const int*)d_in[27]; const int* dst_p2p = (const int*)d_in[28];
    const int* src_p2a = (const int*)d_in[29]; const int* dst_p2a = (const int*)d_in[30];
    const int* src_a2p = (const int*)d_in[31]; const int* dst_a2p = (const int*)d_in[32];
    const int* src_a2a = (const int*)d_in[33]; const int* dst_a2a = (const int*)d_in[34];
    int E_p2p = in_sizes[27], E_p2a = in_sizes[29], E_a2p = in_sizes[31], E_a2a = in_sizes[33];
    int E_tot = E_p2p + E_a2p + E_p2a + E_a2a;

    float* out = (float*)d_out;
    float* outP = out;
    float* outA = out + (long long)NP * 64;
    float* outS = out + (long long)(NP + NA) * 64;

    // ---- workspace layout ----
    float* ws = (float*)d_ws;
    float* WhP = ws; ws += (long long)NP * 64;
    float* WhA = ws; ws += (long long)NA * 64;
    u16* z_p2p = (u16*)ws; ws += (long long)NP * 32;
    u16* z_p2a = (u16*)ws; ws += (long long)NP * 32;
    u16* z_a2p = (u16*)ws; ws += (long long)NA * 32;
    u16* z_a2a = (u16*)ws; ws += (long long)NA * 32;
    float* ss_p2p = ws; ws += NP;  float* sd_p2p = ws; ws += NP;
    float* ss_p2a = ws; ws += NP;  float* sd_p2a = ws; ws += NA;
    float* ss_a2p = ws; ws += NA;  float* sd_a2p = ws; ws += NP;
    float* ss_a2a = ws; ws += NA;  float* sd_a2a = ws; ws += NA;
    // ---- zeroed-every-call region (one tiny memset) ----
    float* zreg = ws;
    int*   cursor0 = (int*)ws; ws += NBUCK;
    float* den2 = ws; ws += 2;
    float* numP = ws; ws += 64;       // raw feature-space numerators
    float* numA = ws; ws += 64;
    size_t zbytes = (size_t)((char*)ws - (char*)zreg);
    // ---- rest ----
    int* iw = (int*)ws;
    int* ebuf = iw; iw += NBUCK * CAP;
    u16* ssrc = (u16*)iw; iw += (E_tot + 1) / 2;
    int* offs = iw; iw += NBINS + 1;

    const int T = 256;
    int nblk = (E_tot + CH - 1) / CH;

    hipMemsetAsync(zreg, 0, zbytes, stream);

    // ---- k1: scatter | xform (wave-items) | state-accumulate ----
    K1Args K1;
    K1.s0 = src_p2p; K1.d0 = dst_p2p; K1.s1 = src_a2p; K1.d1 = dst_a2p;
    K1.s2 = src_p2a; K1.d2 = dst_p2a; K1.s3 = src_a2a; K1.d3 = dst_a2a;
    K1.E0 = E_p2p; K1.E1 = E_a2p; K1.E2 = E_p2a; K1.E3 = E_a2a;
    K1.Etot = E_tot; K1.nblk = nblk;
    K1.cursor0 = cursor0; K1.ebuf = ebuf;
    K1.feat_P = feat_P; K1.feat_A = feat_A; K1.feat_S = feat_S;
    K1.W_P = W_P; K1.b_P = b_P; K1.W_A = W_A; K1.b_A = b_A;
    K1.W_p2p = W_p2p; K1.b_p2p = b_p2p; K1.W_p2a = W_p2a; K1.b_p2a = b_p2a;
    K1.W_a2p = W_a2p; K1.b_a2p = b_a2p; K1.W_a2a = W_a2a; K1.b_a2a = b_a2a;
    K1.a_p2p = a_p2p; K1.a_p2a = a_p2a; K1.a_a2p = a_a2p; K1.a_a2a = a_a2a;
    K1.WhP = WhP; K1.WhA = WhA;
    K1.z_p2p = z_p2p; K1.z_p2a = z_p2a; K1.z_a2p = z_a2p; K1.z_a2a = z_a2a;
    K1.ss_p2p = ss_p2p; K1.sd_p2p = sd_p2p; K1.ss_p2a = ss_p2a; K1.sd_p2a = sd_p2a;
    K1.ss_a2p = ss_a2p; K1.sd_a2p = sd_a2p; K1.ss_a2a = ss_a2a; K1.sd_a2a = sd_a2a;
    K1.W_p2s = W_p2s; K1.b_p2s = b_p2s; K1.a_p2s = a_p2s;
    K1.W_a2s = W_a2s; K1.b_a2s = b_a2s; K1.a_a2s = a_a2s;
    K1.W_in = W_in; K1.b_in = b_in;
    K1.numP = numP; K1.numA = numA; K1.den2 = den2;
    k1_kernel<<<nblk + XWB + SB_P + SB_A, T, 0, stream>>>(K1);

    // ---- k2: fine_sort (u16 packed) | finalize ----
    K2Args K2;
    K2.ebuf = ebuf; K2.cursor0 = cursor0; K2.ssrc = ssrc; K2.offs = offs;
    K2.feat_S = feat_S;
    K2.W_p2s = W_p2s; K2.b_p2s = b_p2s; K2.W_a2s = W_a2s; K2.b_a2s = b_a2s;
    K2.W_in = W_in; K2.b_in = b_in;
    K2.numP = numP; K2.numA = numA; K2.den2 = den2; K2.outS = outS;
    k2_kernel<<<NBUCK + 1, T, 0, stream>>>(K2);

    // ---- k3: gat_all pure ----
    gat_all<<<((NP + NA) * 64 + T - 1) / T, T, 0, stream>>>(ssrc, offs,
        WhP, outP, WhA, outA,
        ss_p2p, sd_p2p, z_p2p, ss_a2p, sd_a2p, z_a2p,
        ss_p2a, sd_p2a, z_p2a, ss_a2a, sd_a2a, z_a2a);
}

// Round 18
// 131.843 us; speedup vs baseline: 1.0625x; 1.0625x over previous
//
#include <hip/hip_runtime.h>
#include <math.h>

#define ALPHA 0.2f
#define NP 50000
#define NA 25000
#define NBINS 150000          // P: 2*NP interleaved bins, then A: 2*NA
#define ABASE 100000          // bin base for A nodes
#define NBUCK 586             // ceil(NBINS/256)
#define CH 4096               // edges per scatter block (= 16*256, static unroll)
#define CAP 8192              // fixed bucket region capacity in ebuf (max observed ~3.9k)
#define GP ((NP + 63) / 64)   // 782 xform-P blocks
#define GA ((NA + 63) / 64)   // 391 xform-A blocks
#define SB_P 384              // state-accum blocks for P
#define SB_A 192              // state-accum blocks for A

typedef unsigned short u16;
typedef __attribute__((ext_vector_type(8))) short bf16x8;
typedef __attribute__((ext_vector_type(8))) unsigned short u16x8;
typedef __attribute__((ext_vector_type(4))) float f32x4;

__device__ __forceinline__ float bf2f(u16 u) { return __uint_as_float(((unsigned)u) << 16); }
__device__ __forceinline__ u16 f2bf(float f) {
    unsigned x = __float_as_uint(f);
    return (u16)((x + 0x7fffu + ((x >> 16) & 1u)) >> 16);   // RNE
}

// =============== args ===============
struct K1Args {      // scatter | state-accumulate
    const int *s0, *d0, *s1, *d1, *s2, *d2, *s3, *d3;
    int E0, E1, E2, E3, Etot, nblk;
    int *cursor0, *ebuf;
    const float *feat_P, *feat_A, *feat_S;
    const float *W_p2s, *b_p2s, *a_p2s, *W_a2s, *b_a2s, *a_a2s, *W_in, *b_in;
    float *numP, *numA, *den2;   // num* = raw feature-space numerators (64 each)
};

struct K2Args {      // fine_sort | xform P | xform A | finalize
    const int *ebuf; const int *cursor0;
    u16 *ssrc; int *offs;
    const float *feat_P, *feat_A, *feat_S;
    const float *W_P, *b_P, *W_A, *b_A, *W_p2p, *b_p2p, *W_p2a, *b_p2a,
                *W_a2p, *b_a2p, *W_a2a, *b_a2a, *W_p2s, *b_p2s, *W_a2s, *b_a2s,
                *W_in, *b_in;
    const float *a_p2p, *a_p2a, *a_a2p, *a_a2a;
    float *WhP, *WhA;
    u16 *z_p2p, *z_p2a, *z_a2p, *z_a2a;
    float *ss_p2p, *sd_p2p, *ss_p2a, *sd_p2a, *ss_a2p, *sd_a2p, *ss_a2a, *sd_a2a;
    const float *numP, *numA, *den2;
    float *outS;
};

// =============== edge decode ===============
__device__ __forceinline__ void edge_decode(int k,
    const int* __restrict__ s0, const int* __restrict__ d0, int E0,
    const int* __restrict__ s1, const int* __restrict__ d1, int E1,
    const int* __restrict__ s2, const int* __restrict__ d2, int E2,
    const int* __restrict__ s3, const int* __restrict__ d3,
    int& src, int& bin) {
    if (k < E0) { src = s0[k]; bin = 2 * d0[k]; return; }
    k -= E0; if (k < E1) { src = s1[k]; bin = 2 * d1[k] + 1; return; }
    k -= E1; if (k < E2) { src = s2[k]; bin = ABASE + 2 * d2[k]; return; }
    k -= E2; src = s3[k]; bin = ABASE + 2 * d3[k] + 1;
}

// =============== k1: scatter | state-accumulate (feature-space, linearity trick) ===============
__global__ __launch_bounds__(256) void k1_kernel(K1Args A) {
    __shared__ int h[NBUCK];
    __shared__ int base[NBUCK];
    int bid = blockIdx.x;
    int tid = threadIdx.x;
    if (bid < A.nblk) {
        // ---- scatter role: window reservation into fixed bucket regions ----
        for (int i = tid; i < NBUCK; i += 256) h[i] = 0;
        __syncthreads();
        int b0 = bid * CH;
        int b1 = min(b0 + CH, A.Etot);
        int cbin[16], csrc[16];
#pragma unroll
        for (int it = 0; it < 16; ++it) {
            int i = b0 + it * 256 + tid;
            int bin = -1, src = 0;
            if (i < b1)
                edge_decode(i, A.s0, A.d0, A.E0, A.s1, A.d1, A.E1,
                            A.s2, A.d2, A.E2, A.s3, A.d3, src, bin);
            cbin[it] = bin; csrc[it] = src;
            if (bin >= 0) atomicAdd(&h[bin >> 8], 1);
        }
        __syncthreads();
        for (int i = tid; i < NBUCK; i += 256) {
            int c = h[i];
            base[i] = c ? (i * CAP + atomicAdd(&A.cursor0[i], c)) : 0;
            h[i] = 0;                           // reuse as local cursor
        }
        __syncthreads();
#pragma unroll
        for (int it = 0; it < 16; ++it) {
            int bin = cbin[it];
            if (bin >= 0) {
                int bk = bin >> 8;
                int pos = base[bk] + atomicAdd(&h[bk], 1);
                if (pos < (bk + 1) * CAP)       // capacity guard (never hit)
                    A.ebuf[pos] = csrc[it] | ((bin & 255) << 16);
            }
        }
        return;
    }
    // ---- state-accumulate role: num_raw += w*x, den += w over ALL nodes ----
    float* red = (float*)h;                     // reuse LDS
    int sb = bid - A.nblk;
    bool isP = sb < SB_P;
    int bidl = isP ? sb : sb - SB_P;
    int nb = isP ? SB_P : SB_A;
    int N = isP ? NP : NA;
    const float* X   = isP ? A.feat_P : A.feat_A;
    const float* W   = isP ? A.W_p2s  : A.W_a2s;
    const float* b   = isP ? A.b_p2s  : A.b_a2s;
    const float* a   = isP ? A.a_p2s  : A.a_a2s;   // [128]: src-half then dst-half
    float* num       = isP ? A.numP   : A.numA;
    float* den       = isP ? &A.den2[0] : &A.den2[1];
    int lane = tid & 63, wv = tid >> 6;
    float v = 0.f;
    for (int c = 0; c < 64; ++c) v = fmaf(W[lane * 64 + c], a[c], v);
    float t0 = b[lane] * a[lane];
    float whc = A.b_in[lane];
    for (int k = 0; k < 64; ++k) whc = fmaf(A.feat_S[k], A.W_in[k * 64 + lane], whc);
    float t1 = whc * a[64 + lane];
#pragma unroll
    for (int o = 1; o < 64; o <<= 1) {
        t0 += __shfl_xor(t0, o, 64);
        t1 += __shfl_xor(t1, o, 64);
    }
    float cbias = t0 + t1;                      // c0 + sdst
    float accx = 0.f, accd = 0.f;
    int gw = bidl * 4 + wv, waves = nb * 4;
    for (int r = gw; r < N; r += waves) {
        float x = X[(long long)r * 64 + lane];  // coalesced
        float ss = x * v;
#pragma unroll
        for (int o = 1; o < 64; o <<= 1) ss += __shfl_xor(ss, o, 64);
        float e = ss + cbias;
        e = e > 0.f ? e : ALPHA * e;
        float w = __expf(e);
        accx = fmaf(w, x, accx);
        accd += w;
    }
    red[wv * 64 + lane] = accx;
    if (lane == 0) red[256 + wv] = accd;
    __syncthreads();
    if (tid < 64) {
        float t = red[tid] + red[64 + tid] + red[128 + tid] + red[192 + tid];
        atomicAdd(&num[tid], t);
    }
    if (tid == 64) atomicAdd(den, red[256] + red[257] + red[258] + red[259]);
}

// =============== in-block exclusive scan of 586 bucket counts (clamped to CAP) ===============
__device__ void scan_counts(const int* __restrict__ counts, int* sstart) {
    __shared__ int wtot_sb[4];
    int tid = threadIdx.x, lane = tid & 63, wv = tid >> 6;
    int carry = 0;
    for (int c = 0; c < 3; ++c) {
        int i = c * 256 + tid;
        int v = (i < NBUCK) ? min(counts[i], CAP) : 0;
        int x = v;
#pragma unroll
        for (int o = 1; o < 64; o <<= 1) {
            int y = __shfl_up(x, o, 64);
            if (lane >= o) x += y;
        }
        if (lane == 63) wtot_sb[wv] = x;
        __syncthreads();
        int woff = carry;
        for (int j = 0; j < wv; ++j) woff += wtot_sb[j];
        int ctot = wtot_sb[0] + wtot_sb[1] + wtot_sb[2] + wtot_sb[3];
        if (i < NBUCK) sstart[i] = x + woff - v;
        __syncthreads();
        carry += ctot;
    }
    if (tid == 0) sstart[NBUCK] = carry;
    __syncthreads();
}

// =============== MFMA 3-matrix transform (waves 0-2; wave 3 exits) ===============
__device__ __forceinline__ void xform_body3(int bid,
    const float* __restrict__ X, int N,
    const float* __restrict__ W0, const float* __restrict__ b0, float* __restrict__ Wh,
    const float* __restrict__ dA, float* __restrict__ sdA,
    const float* __restrict__ dB, float* __restrict__ sdB,
    const float* __restrict__ W1, const float* __restrict__ b1, u16* __restrict__ z1,
    const float* __restrict__ v1, float* __restrict__ s1,
    const float* __restrict__ W2, const float* __restrict__ b2, u16* __restrict__ z2,
    const float* __restrict__ v2, float* __restrict__ s2)
{
    int tid = threadIdx.x, wv = tid >> 6, lane = tid & 63;
    if (wv == 3) return;                        // 3 matrices only
    int g = lane >> 4, li = lane & 15;
    const float* Wm = wv == 0 ? W0 : wv == 1 ? W1 : W2;
    const float* bm = wv == 0 ? b0 : wv == 1 ? b1 : b2;
    const float* dv = wv == 0 ? dA : wv == 1 ? v1 : v2;
    float* sm       = wv == 0 ? sdA : wv == 1 ? s1 : s2;
    u16* zm         = wv == 1 ? z1 : wv == 2 ? z2 : nullptr;

    bf16x8 Bf[4][2];
#pragma unroll
    for (int cb = 0; cb < 4; ++cb)
#pragma unroll
        for (int kc = 0; kc < 2; ++kc) {
            bf16x8 t;
#pragma unroll
            for (int j = 0; j < 8; ++j)
                t[j] = (short)f2bf(Wm[(kc * 32 + g * 8 + j) * 64 + cb * 16 + li]);
            Bf[cb][kc] = t;
        }
    float bl[4], dvl[4], dbl[4];
#pragma unroll
    for (int cb = 0; cb < 4; ++cb) {
        bl[cb]  = bm[cb * 16 + li];
        dvl[cb] = dv[cb * 16 + li];
        dbl[cb] = (wv == 0) ? dB[cb * 16 + li] : 0.f;
    }
    int base0 = bid * 64;
#pragma unroll
    for (int rt = 0; rt < 4; ++rt) {
        int rbase = base0 + rt * 16;
        if (rbase >= N) break;
        int rowC = min(rbase + li, N - 1);
        bf16x8 Af[2];
#pragma unroll
        for (int kc = 0; kc < 2; ++kc) {
            const float* xp = X + (long long)rowC * 64 + kc * 32 + g * 8;
            float4 x0 = *(const float4*)xp;
            float4 x1 = *(const float4*)(xp + 4);
            bf16x8 t;
            t[0] = (short)f2bf(x0.x); t[1] = (short)f2bf(x0.y);
            t[2] = (short)f2bf(x0.z); t[3] = (short)f2bf(x0.w);
            t[4] = (short)f2bf(x1.x); t[5] = (short)f2bf(x1.y);
            t[6] = (short)f2bf(x1.z); t[7] = (short)f2bf(x1.w);
            Af[kc] = t;
        }
        f32x4 acc[4] = {{0,0,0,0},{0,0,0,0},{0,0,0,0},{0,0,0,0}};
#pragma unroll
        for (int kc = 0; kc < 2; ++kc)
#pragma unroll
            for (int cb = 0; cb < 4; ++cb)
                acc[cb] = __builtin_amdgcn_mfma_f32_16x16x32_bf16(Af[kc], Bf[cb][kc], acc[cb], 0, 0, 0);
        float pd[4] = {0,0,0,0}, pb[4] = {0,0,0,0};
#pragma unroll
        for (int cb = 0; cb < 4; ++cb)
#pragma unroll
            for (int r = 0; r < 4; ++r) {
                float val = acc[cb][r] + bl[cb];
                acc[cb][r] = val;
                pd[r] = fmaf(val, dvl[cb], pd[r]);
                pb[r] = fmaf(val, dbl[cb], pb[r]);
            }
#pragma unroll
        for (int o = 1; o < 16; o <<= 1)
#pragma unroll
            for (int r = 0; r < 4; ++r) {
                pd[r] += __shfl_xor(pd[r], o, 64);
                pb[r] += __shfl_xor(pb[r], o, 64);
            }
        int rg = rbase + g * 4;
        if (li == 0) {
#pragma unroll
            for (int r = 0; r < 4; ++r) {
                int row = rg + r;
                if (row < N) {
                    sm[row] = pd[r];
                    if (wv == 0) sdB[row] = pb[r];
                }
            }
        }
        if (wv == 0) {
#pragma unroll
            for (int r = 0; r < 4; ++r) {
                int row = rg + r;
                if (row < N)
#pragma unroll
                    for (int cb = 0; cb < 4; ++cb)
                        Wh[(long long)row * 64 + cb * 16 + li] = acc[cb][r];
            }
        } else {
#pragma unroll
            for (int r = 0; r < 4; ++r) {
                int row = rg + r;
                if (row < N)
#pragma unroll
                    for (int cb = 0; cb < 4; ++cb)
                        zm[(long long)row * 64 + cb * 16 + li] = f2bf(acc[cb][r]);
            }
        }
    }
}

// =============== k2: fine_sort (u16) | xform P | xform A | state finalize ===============
__global__ __launch_bounds__(256) void k2_kernel(K2Args A) {
    __shared__ int smem_i[NBUCK + 1 + 768 + 4];     // sstart | lcnt | loff | lcur | wtot
    __shared__ u16 lsrc[CAP];
    int bid = blockIdx.x;
    int tid = threadIdx.x, lane = tid & 63, wv = tid >> 6;
    if (bid < NBUCK) {
        // ---- fine_sort role: CAP region -> PACKED bin-sorted u16 ssrc + flat offs ----
        int* sstart = smem_i;
        int* lcnt = smem_i + NBUCK + 1;
        int* loff = lcnt + 256;
        int* lcur = loff + 256;
        int* wtot = lcur + 256;
        int b = bid;
        scan_counts(A.cursor0, sstart);
        int pstart = sstart[b];
        int rstart = b * CAP;
        int cnt = min(A.cursor0[b], CAP);
        lcnt[tid] = 0;
        __syncthreads();
        for (int e = tid; e < cnt; e += 256)
            atomicAdd(&lcnt[((unsigned)A.ebuf[rstart + e]) >> 16], 1);
        __syncthreads();
        int v = lcnt[tid];
        int x = v;
#pragma unroll
        for (int o = 1; o < 64; o <<= 1) {
            int y = __shfl_up(x, o, 64);
            if (lane >= o) x += y;
        }
        if (lane == 63) wtot[wv] = x;
        __syncthreads();
        int woff = 0;
        for (int j = 0; j < wv; ++j) woff += wtot[j];
        int excl = x + woff - v;
        loff[tid] = excl;
        lcur[tid] = excl;
        __syncthreads();
        for (int e = tid; e < cnt; e += 256) {
            int val = A.ebuf[rstart + e];
            int pos = atomicAdd(&lcur[((unsigned)val) >> 16], 1);
            lsrc[pos] = (u16)(val & 0xFFFF);
        }
        __syncthreads();
        for (int i = tid; i < cnt; i += 256) A.ssrc[pstart + i] = lsrc[i];   // coalesced u16
        int gb = b * 256 + tid;
        if (gb < NBINS) A.offs[gb] = pstart + loff[tid];
        if (b == 0 && tid == 0) A.offs[NBINS] = sstart[NBUCK];
        return;
    }
    bid -= NBUCK;
    if (bid < GP) {
        xform_body3(bid, A.feat_P, NP,
                    A.W_P, A.b_P, A.WhP, A.a_p2p + 64, A.sd_p2p, A.a_a2p + 64, A.sd_a2p,
                    A.W_p2p, A.b_p2p, A.z_p2p, A.a_p2p, A.ss_p2p,
                    A.W_p2a, A.b_p2a, A.z_p2a, A.a_p2a, A.ss_p2a);
        return;
    }
    bid -= GP;
    if (bid < GA) {
        xform_body3(bid, A.feat_A, NA,
                    A.W_A, A.b_A, A.WhA, A.a_p2a + 64, A.sd_p2a, A.a_a2a + 64, A.sd_a2a,
                    A.W_a2p, A.b_a2p, A.z_a2p, A.a_a2p, A.ss_a2p,
                    A.W_a2a, A.b_a2a, A.z_a2a, A.a_a2a, A.ss_a2a);
        return;
    }
    // ---- finalize role ----
    if (tid < 64) {
        int c = tid;
        float whc = A.b_in[c];
        for (int k = 0; k < 64; ++k) whc = fmaf(A.feat_S[k], A.W_in[k * 64 + c], whc);
        float mp = 0.f, ma = 0.f;
        for (int k = 0; k < 64; ++k) {
            mp = fmaf(A.numP[k], A.W_p2s[k * 64 + c], mp);
            ma = fmaf(A.numA[k], A.W_a2s[k * 64 + c], ma);
        }
        float r = whc + mp / A.den2[0] + A.b_p2s[c] + ma / A.den2[1] + A.b_a2s[c];
        A.outS[c] = fmaxf(r, 0.f);
    }
}

// =============== per-segment gather, 8 edges in flight (R8 structure, u16 ssrc) ===============
__device__ __forceinline__ void seg_gat_g8(const u16* __restrict__ ssrc, int s0, int s1,
                                           const float* __restrict__ ss, float sd,
                                           const u16* __restrict__ z, int lane,
                                           float* __restrict__ acc) {
    int cnt = s1 - s0;
    if (cnt <= 0) return;
    int egrp = lane >> 3, cg8 = (lane & 7) * 8;
    if (cnt <= 64) {                    // fast path (deg <= 64: essentially always)
        int s = 0; float w = 0.f;
        if (lane < cnt) {
            s = (int)ssrc[s0 + lane];   // coalesced u16
            float e = ss[s] + sd;
            e = e > 0.f ? e : ALPHA * e;
            w = __expf(e);
        }
        float den = w;
#pragma unroll
        for (int o = 32; o > 0; o >>= 1) den += __shfl_xor(den, o, 64);
        w *= 1.f / den;
        int nit = (cnt + 7) >> 3;
        for (int it = 0; it < nit; ++it) {
            int ei = it * 8 + egrp;
            float wt = __shfl(w, ei, 64);   // 0 for ei >= cnt
            int   st = __shfl(s, ei, 64);
            u16x8 q = *(const u16x8*)(z + (long long)st * 64 + cg8);
#pragma unroll
            for (int j = 0; j < 8; ++j)
                acc[j] = fmaf(wt, bf2f(q[j]), acc[j]);
        }
    } else {                            // general path (rare)
        float den = 0.f;
        for (int i = s0 + lane; i < s1; i += 64) {
            float e = ss[(int)ssrc[i]] + sd; e = e > 0.f ? e : ALPHA * e; den += __expf(e);
        }
#pragma unroll
        for (int o = 32; o > 0; o >>= 1) den += __shfl_xor(den, o, 64);
        float inv = 1.f / den;
        for (int c = s0; c < s1; c += 64) {
            int i = c + lane; int s = 0; float w = 0.f;
            if (i < s1) {
                s = (int)ssrc[i];
                float e = ss[s] + sd; e = e > 0.f ? e : ALPHA * e;
                w = __expf(e) * inv;
            }
            int cc = min(64, s1 - c);
            int nit = (cc + 7) >> 3;
            for (int it = 0; it < nit; ++it) {
                int ei = it * 8 + egrp;
                float wt = __shfl(w, ei, 64);
                int   st = __shfl(s, ei, 64);
                u16x8 q = *(const u16x8*)(z + (long long)st * 64 + cg8);
#pragma unroll
                for (int j = 0; j < 8; ++j)
                    acc[j] = fmaf(wt, bf2f(q[j]), acc[j]);
            }
        }
    }
}

// =============== gat_all: PURE kernel (R8-proven) ===============
__global__ __launch_bounds__(256) void gat_all(
    const u16* __restrict__ ssrc, const int* __restrict__ offs,
    const float* __restrict__ WhP, float* __restrict__ outP,
    const float* __restrict__ WhA, float* __restrict__ outA,
    const float* __restrict__ ss_p2p, const float* __restrict__ sd_p2p, const u16* __restrict__ z_p2p,
    const float* __restrict__ ss_a2p, const float* __restrict__ sd_a2p, const u16* __restrict__ z_a2p,
    const float* __restrict__ ss_p2a, const float* __restrict__ sd_p2a, const u16* __restrict__ z_p2a,
    const float* __restrict__ ss_a2a, const float* __restrict__ sd_a2a, const u16* __restrict__ z_a2a) {
    int lane = threadIdx.x & 63;
    int g = (blockIdx.x * blockDim.x + threadIdx.x) >> 6;   // wave id = node id
    if (g >= NP + NA) return;                               // wave-uniform
    bool isP = g < NP;
    int d = isP ? g : g - NP;
    int bin0 = isP ? 2 * d : ABASE + 2 * d;
    int e0 = offs[bin0], e1 = offs[bin0 + 1], e2 = offs[bin0 + 2];
    float acc[8] = {0.f, 0.f, 0.f, 0.f, 0.f, 0.f, 0.f, 0.f};
    if (isP) {
        seg_gat_g8(ssrc, e0, e1, ss_p2p, sd_p2p[d], z_p2p, lane, acc);
        seg_gat_g8(ssrc, e1, e2, ss_a2p, sd_a2p[d], z_a2p, lane, acc);
    } else {
        seg_gat_g8(ssrc, e0, e1, ss_p2a, sd_p2a[d], z_p2a, lane, acc);
        seg_gat_g8(ssrc, e1, e2, ss_a2a, sd_a2a[d], z_a2a, lane, acc);
    }
#pragma unroll
    for (int o = 8; o <= 32; o <<= 1)
#pragma unroll
        for (int j = 0; j < 8; ++j)
            acc[j] += __shfl_xor(acc[j], o, 64);
    if (lane < 8) {
        const float* Wh = isP ? WhP : WhA;
        float* outp = isP ? outP : outA;
        const float* sp = &Wh[(long long)d * 64 + lane * 8];
        float4 s0v = *(const float4*)sp;
        float4 s1v = *(const float4*)(sp + 4);
        float4 r0, r1;
        r0.x = fmaxf(s0v.x + acc[0], 0.f); r0.y = fmaxf(s0v.y + acc[1], 0.f);
        r0.z = fmaxf(s0v.z + acc[2], 0.f); r0.w = fmaxf(s0v.w + acc[3], 0.f);
        r1.x = fmaxf(s1v.x + acc[4], 0.f); r1.y = fmaxf(s1v.y + acc[5], 0.f);
        r1.z = fmaxf(s1v.z + acc[6], 0.f); r1.w = fmaxf(s1v.w + acc[7], 0.f);
        float* op = &outp[(long long)d * 64 + lane * 8];
        *(float4*)op = r0;
        *(float4*)(op + 4) = r1;
    }
}

extern "C" void kernel_launch(void* const* d_in, const int* in_sizes, int n_in,
                              void* d_out, int out_size, void* d_ws, size_t ws_size,
                              hipStream_t stream) {
    const float* feat_P = (const float*)d_in[0];
    const float* feat_A = (const float*)d_in[1];
    const float* feat_S = (const float*)d_in[2];
    const float* W_P   = (const float*)d_in[3];  const float* b_P   = (const float*)d_in[4];
    const float* W_A   = (const float*)d_in[5];  const float* b_A   = (const float*)d_in[6];
    const float* W_p2p = (const float*)d_in[7];  const float* b_p2p = (const float*)d_in[8];
    const float* W_p2a = (const float*)d_in[9];  const float* b_p2a = (const float*)d_in[10];
    const float* W_a2p = (const float*)d_in[11]; const float* b_a2p = (const float*)d_in[12];
    const float* W_a2a = (const float*)d_in[13]; const float* b_a2a = (const float*)d_in[14];
    const float* W_p2s = (const float*)d_in[15]; const float* b_p2s = (const float*)d_in[16];
    const float* W_a2s = (const float*)d_in[17]; const float* b_a2s = (const float*)d_in[18];
    const float* W_in  = (const float*)d_in[19]; const float* b_in  = (const float*)d_in[20];
    const float* a_p2p = (const float*)d_in[21];
    const float* a_p2a = (const float*)d_in[22];
    const float* a_a2p = (const float*)d_in[23];
    const float* a_a2a = (const float*)d_in[24];
    const float* a_p2s = (const float*)d_in[25];
    const float* a_a2s = (const float*)d_in[26];
    const int* src_p2p = (const int*)d_in[27]; const int* dst_p2p = (const int*)d_in[28];
    const int* src_p2a = (const int*)d_in[29]; const int* dst_p2a = (const int*)d_in[30];
    const int* src_a2p = (const int*)d_in[31]; const int* dst_a2p = (const int*)d_in[32];
    const int* src_a2a = (const int*)d_in[33]; const int* dst_a2a = (const int*)d_in[34];
    int E_p2p = in_sizes[27], E_p2a = in_sizes[29], E_a2p = in_sizes[31], E_a2a = in_sizes[33];
    int E_tot = E_p2p + E_a2p + E_p2a + E_a2a;

    float* out = (float*)d_out;
    float* outP = out;
    float* outA = out + (long long)NP * 64;
    float* outS = out + (long long)(NP + NA) * 64;

    // ---- workspace layout ----
    float* ws = (float*)d_ws;
    float* WhP = ws; ws += (long long)NP * 64;
    float* WhA = ws; ws += (long long)NA * 64;
    u16* z_p2p = (u16*)ws; ws += (long long)NP * 32;
    u16* z_p2a = (u16*)ws; ws += (long long)NP * 32;
    u16* z_a2p = (u16*)ws; ws += (long long)NA * 32;
    u16* z_a2a = (u16*)ws; ws += (long long)NA * 32;
    float* ss_p2p = ws; ws += NP;  float* sd_p2p = ws; ws += NP;
    float* ss_p2a = ws; ws += NP;  float* sd_p2a = ws; ws += NA;
    float* ss_a2p = ws; ws += NA;  float* sd_a2p = ws; ws += NP;
    float* ss_a2a = ws; ws += NA;  float* sd_a2a = ws; ws += NA;
    // ---- zeroed-every-call region (one tiny memset) ----
    float* zreg = ws;
    int*   cursor0 = (int*)ws; ws += NBUCK;
    float* den2 = ws; ws += 2;
    float* numP = ws; ws += 64;       // raw feature-space numerators
    float* numA = ws; ws += 64;
    size_t zbytes = (size_t)((char*)ws - (char*)zreg);
    // ---- rest ----
    int* iw = (int*)ws;
    int* ebuf = iw; iw += NBUCK * CAP;
    u16* ssrc = (u16*)iw; iw += (E_tot + 1) / 2;
    int* offs = iw; iw += NBINS + 1;

    const int T = 256;
    int nblk = (E_tot + CH - 1) / CH;

    hipMemsetAsync(zreg, 0, zbytes, stream);

    // ---- k1: scatter | state-accumulate ----
    K1Args K1;
    K1.s0 = src_p2p; K1.d0 = dst_p2p; K1.s1 = src_a2p; K1.d1 = dst_a2p;
    K1.s2 = src_p2a; K1.d2 = dst_p2a; K1.s3 = src_a2a; K1.d3 = dst_a2a;
    K1.E0 = E_p2p; K1.E1 = E_a2p; K1.E2 = E_p2a; K1.E3 = E_a2a;
    K1.Etot = E_tot; K1.nblk = nblk;
    K1.cursor0 = cursor0; K1.ebuf = ebuf;
    K1.feat_P = feat_P; K1.feat_A = feat_A; K1.feat_S = feat_S;
    K1.W_p2s = W_p2s; K1.b_p2s = b_p2s; K1.a_p2s = a_p2s;
    K1.W_a2s = W_a2s; K1.b_a2s = b_a2s; K1.a_a2s = a_a2s;
    K1.W_in = W_in; K1.b_in = b_in;
    K1.numP = numP; K1.numA = numA; K1.den2 = den2;
    k1_kernel<<<nblk + SB_P + SB_A, T, 0, stream>>>(K1);

    // ---- k2: fine_sort (u16) | xform P | xform A | finalize ----
    K2Args K2;
    K2.ebuf = ebuf; K2.cursor0 = cursor0; K2.ssrc = ssrc; K2.offs = offs;
    K2.feat_P = feat_P; K2.feat_A = feat_A; K2.feat_S = feat_S;
    K2.W_P = W_P; K2.b_P = b_P; K2.W_A = W_A; K2.b_A = b_A;
    K2.W_p2p = W_p2p; K2.b_p2p = b_p2p; K2.W_p2a = W_p2a; K2.b_p2a = b_p2a;
    K2.W_a2p = W_a2p; K2.b_a2p = b_a2p; K2.W_a2a = W_a2a; K2.b_a2a = b_a2a;
    K2.W_p2s = W_p2s; K2.b_p2s = b_p2s; K2.W_a2s = W_a2s; K2.b_a2s = b_a2s;
    K2.W_in = W_in; K2.b_in = b_in;
    K2.a_p2p = a_p2p; K2.a_p2a = a_p2a; K2.a_a2p = a_a2p; K2.a_a2a = a_a2a;
    K2.WhP = WhP; K2.WhA = WhA;
    K2.z_p2p = z_p2p; K2.z_p2a = z_p2a; K2.z_a2p = z_a2p; K2.z_a2a = z_a2a;
    K2.ss_p2p = ss_p2p; K2.sd_p2p = sd_p2p; K2.ss_p2a = ss_p2a; K2.sd_p2a = sd_p2a;
    K2.ss_a2p = ss_a2p; K2.sd_a2p = sd_a2p; K2.ss_a2a = ss_a2a; K2.sd_a2a = sd_a2a;
    K2.numP = numP; K2.numA = numA; K2.den2 = den2; K2.outS = outS;
    k2_kernel<<<NBUCK + GP + GA + 1, T, 0, stream>>>(K2);

    // ---- k3: gat_all pure ----
    gat_all<<<((NP + NA) * 64 + T - 1) / T, T, 0, stream>>>(ssrc, offs,
        WhP, outP, WhA, outA,
        ss_p2p, sd_p2p, z_p2p, ss_a2p, sd_a2p, z_a2p,
        ss_p2a, sd_p2a, z_p2a, ss_a2a, sd_a2a, z_a2a);
}